// Round 19
// baseline (212.971 us; speedup 1.0000x reference)
//
#include <hip/hip_runtime.h>
#include <hip/hip_bf16.h>

// Problem constants
#define NN    8
#define CC    32
#define HH    48
#define WW    48
#define OCC   32
#define HID   256
#define FEAT  288          // C*K*K
#define RTOT  9216         // (H*S)*(W*S)
#define COLS  9216         // FEAT*OC
#define XUP   96
#define YUP   96
#define OUTSZ (NN*OCC*XUP*YUP)   // 2,359,296 floats

using bf16x8 = __attribute__((ext_vector_type(8))) __bf16;
using bf16x4 = __attribute__((ext_vector_type(4))) __bf16;
using f32x4  = __attribute__((ext_vector_type(4))) float;

#define GLOAD_LDS16(gp, lp)                                                        \
  __builtin_amdgcn_global_load_lds((const __attribute__((address_space(1))) void*)(gp), \
                                   (__attribute__((address_space(3))) void*)(lp), 16, 0, 0)

// ---------------------------------------------------------------------------
// Kernel 1: hmid = relu(v @ w1 + b1), bf16, MFMA A-fragment order (verified):
//   frag = (r/16)*8 + k/32 ; lane = ((k/8)%4)*16 + r%16 ; elem = k%8
// ---------------------------------------------------------------------------
__global__ void prep_hmid(const float* __restrict__ v, const float* __restrict__ w1,
                          const float* __restrict__ b1, __hip_bfloat16* __restrict__ hmidp) {
  int r = blockIdx.x;      // 0..9215
  int t = threadIdx.x;     // 0..255 = hidden index k
  float v0 = v[r*3+0], v1 = v[r*3+1], v2 = v[r*3+2];
  float val = v0*w1[t] + v1*w1[HID+t] + v2*w1[2*HID+t] + b1[t];
  val = fmaxf(val, 0.0f);
  int dst = ((r>>4)*8 + (t>>5))*512 + ((t>>3)&3)*128 + (r&15)*8 + (t&7);
  hmidp[dst] = __float2bfloat16(val);
}

// ---------------------------------------------------------------------------
// Kernel 2: w2 -> bf16, B-fragment order grouped into 8KB slices (verified):
//   colchunk = col/128 (72), kb = k/32 (8), cg = (col%128)/16 (8),
//   lane = ((k/8)%4)*16 + col%16, elem = k%8
// ---------------------------------------------------------------------------
__global__ void prep_w2(const float* __restrict__ w2, __hip_bfloat16* __restrict__ w2p) {
  int idx = blockIdx.x*256 + threadIdx.x;   // 0 .. 256*9216-1
  int k   = idx / COLS;
  int col = idx % COLS;
  float val = w2[idx];                      // w2[k][col], row-major
  int colchunk = col >> 7;
  int cg   = (col >> 4) & 7;
  int lane = (((k>>3)&3)<<4) | (col & 15);
  int kb   = k >> 5;
  int i    = k & 7;
  int dst  = (((colchunk*8 + kb)*8 + cg)*64 + lane)*8 + i;
  w2p[dst] = __float2bfloat16(val);
}

// ---------------------------------------------------------------------------
// Kernel 3: fused GEMM + apply, BM=64 (R19).
// Block = 512 thr = 8 waves, TWO row-tiles X=2m,2m+1 (SAME h=m -> shared pat).
// Wave wv: rg = wv>>2 (row-tile), colq = wv&3 (col quarter). rg=0/1 twins load
// identical B addresses -> L1/L2 dedup; 288 blocks -> far B traffic HALVED
// (1.36 GB -> 0.68 GB), pat/A staging traffic halved.
// Core mappings = R11/R12-proven with rg/wq substitutions.
// LDS: Atile 32768 + pat 27648 + wc 32768 + biasL = 102,400 (G=2).
// ---------------------------------------------------------------------------
#define BARRIER_LGKM() do {                              \
    asm volatile("s_waitcnt lgkmcnt(0)" ::: "memory");   \
    __builtin_amdgcn_sched_barrier(0);                   \
    __builtin_amdgcn_s_barrier();                        \
  } while (0)

#define ISSUE_HALF(SET, CH, H) do {                                              \
    const char* _b = w2base + ((size_t)((CH)*8 + (H)*4))*8192 + colq*2048        \
                     + (size_t)lane*16;                                          \
    _Pragma("unroll")                                                            \
    for (int _i = 0; _i < 4; ++_i) {                                             \
      SET[0][_i] = *(const bf16x8*)(_b + _i*8192);                               \
      SET[1][_i] = *(const bf16x8*)(_b + _i*8192 + 1024);                        \
    }                                                                            \
  } while (0)

__launch_bounds__(512, 2)
__global__ void fused_main(const float* __restrict__ F_LR,
                           const __hip_bfloat16* __restrict__ hmidp,
                           const __hip_bfloat16* __restrict__ w2p,
                           const float* __restrict__ b2,
                           float* __restrict__ outp,
                           int G, int nch) {
  extern __shared__ __align__(16) char smem[];
  char*   AtileB = smem;                         // 32768B: [rg][mg*8+kb][lane][8]
  __bf16* patB   = (__bf16*)(smem + 32768);      // 27648B: [(c*3+ki)*18+wi][n]
  float*  wc     = (float*)(smem + 60416);       // 32768B: [(colq*2+rg)][ocx][r^swz]
  __bf16* biasL  = (__bf16*)(smem + 93184);      // nch*128 bf16

  const int tid  = threadIdx.x;
  const int lane = tid & 63;
  const int wv   = tid >> 6;                     // 0..7
  const int rg   = wv >> 2;                      // row-tile 0/1
  const int colq = wv & 3;                       // col quarter (GEMM) / row quarter (apply)
  const int blk  = blockIdx.x;
  int pq, g;
  if (G == 2) {            // 288 blocks: xcd = blk&7; pair-of-xcds owns 36 pq's
    int xcd = blk & 7;
    int j   = blk >> 3;    // 0..35
    g       = xcd & 1;
    pq      = (xcd >> 1)*36 + j;   // 0..143
  } else {                 // 144 blocks
    pq = blk;
    g  = 0;
  }
  const int m   = pq / 3;          // X pair: X = 2m (rg=0), 2m+1 (rg=1)
  const int Yh  = pq - m*3;
  const int h   = m;               // (2m)>>1 == (2m+1)>>1 == m
  const int w0  = Yh * 16;
  const int l15 = lane & 15;
  const int qt  = lane >> 4;
  const int oc  = lane & 31;
  const int nh  = lane >> 5;

  const char* w2base = (const char*)w2p + (size_t)g*nch*65536;

  // ---- A tiles -> LDS (2 x 16KB linear, R12-proven pattern) ----
  {
    const int t0 = 6*m + Yh;                     // rowtile for X=2m
    const int tt = (wv < 4) ? t0 : (t0 + 3);     // +3 = rowtile for X=2m+1
    const int wq4 = wv & 3;
    const char* hsrc = (const char*)hmidp + (size_t)tt*16384;
    char* adst = AtileB + (size_t)(wv >> 2)*16384;
    #pragma unroll
    for (int j = 0; j < 4; ++j)
      GLOAD_LDS16(hsrc + j*4096 + wq4*1024 + lane*16, adst + j*4096 + wq4*1024);
  }

  // ---- bias table -> LDS (bf16, one-time) ----
  for (int i = tid; i < nch*128; i += 512)
    biasL[i] = (__bf16)b2[g*nch*128 + i];

  // ---- stage patches (shared by both row-tiles; h identical) ----
  for (int idx = tid; idx < 13824; idx += 512) { // (c*3+ki)=96 x n=8 x wi=18
    int wi = idx % 18;
    int t4 = idx / 18;
    int n  = t4 & 7;
    int t3 = t4 >> 3;                            // c*3+ki
    int ki = t3 % 3;
    int c  = t3 / 3;
    int hh = h - 1 + ki;
    int ww = w0 - 1 + wi;
    float val = 0.f;
    if ((unsigned)hh < (unsigned)HH && (unsigned)ww < (unsigned)WW)
      val = F_LR[((n*CC + c)*HH + hh)*WW + ww];
    patB[(t3*18 + wi)*8 + n] = (__bf16)val;
  }
  asm volatile("s_waitcnt vmcnt(0) lgkmcnt(0)" ::: "memory");
  __builtin_amdgcn_sched_barrier(0);
  __builtin_amdgcn_s_barrier();                  // Atile/pat/bias all visible

  float oacc[8][4];
  #pragma unroll
  for (int i = 0; i < 8; ++i)
    { oacc[i][0]=0.f; oacc[i][1]=0.f; oacc[i][2]=0.f; oacc[i][3]=0.f; }

  // ---- B double buffer (R11 structure; rg twins load same addresses) ----
  bf16x8 bA[2][4], bB[2][4];
  ISSUE_HALF(bA, 0, 0);
  ISSUE_HALF(bB, 0, 1);

  const char* Abase = AtileB + (size_t)rg*16384;

  for (int ch = 0; ch < nch; ++ch) {
    f32x4 acc00 = {0,0,0,0}, acc01 = {0,0,0,0}, acc10 = {0,0,0,0}, acc11 = {0,0,0,0};

    #pragma unroll
    for (int s = 0; s < 4; ++s) {
      bf16x8 a0 = *(const bf16x8*)(Abase + s*1024 + lane*16);
      bf16x8 a1 = *(const bf16x8*)(Abase + 8192 + s*1024 + lane*16);
      acc00 = __builtin_amdgcn_mfma_f32_16x16x32_bf16(a0, bA[0][s], acc00, 0,0,0);
      acc01 = __builtin_amdgcn_mfma_f32_16x16x32_bf16(a0, bA[1][s], acc01, 0,0,0);
      acc10 = __builtin_amdgcn_mfma_f32_16x16x32_bf16(a1, bA[0][s], acc10, 0,0,0);
      acc11 = __builtin_amdgcn_mfma_f32_16x16x32_bf16(a1, bA[1][s], acc11, 0,0,0);
    }
    if (ch + 1 < nch) { ISSUE_HALF(bA, ch+1, 0); }

    #pragma unroll
    for (int s = 0; s < 4; ++s) {
      bf16x8 a0 = *(const bf16x8*)(Abase + (4+s)*1024 + lane*16);
      bf16x8 a1 = *(const bf16x8*)(Abase + 8192 + (4+s)*1024 + lane*16);
      acc00 = __builtin_amdgcn_mfma_f32_16x16x32_bf16(a0, bB[0][s], acc00, 0,0,0);
      acc01 = __builtin_amdgcn_mfma_f32_16x16x32_bf16(a0, bB[1][s], acc01, 0,0,0);
      acc10 = __builtin_amdgcn_mfma_f32_16x16x32_bf16(a1, bB[0][s], acc10, 0,0,0);
      acc11 = __builtin_amdgcn_mfma_f32_16x16x32_bf16(a1, bB[1][s], acc11, 0,0,0);
    }
    if (ch + 1 < nch) { ISSUE_HALF(bB, ch+1, 1); }

    // ---- wc write: block (colq*2+rg): wc[..][ocx][r^swz] = acc + bias ----
    {
      float bias0 = (float)biasL[ch*128 + colq*32 + l15];
      float bias1 = (float)biasL[ch*128 + colq*32 + 16 + l15];
      float* wcb = wc + (size_t)(colq*2 + rg)*1024;
      #pragma unroll
      for (int mg = 0; mg < 2; ++mg) {
        #pragma unroll
        for (int ng = 0; ng < 2; ++ng) {
          f32x4 A = (mg==0) ? (ng==0?acc00:acc01) : (ng==0?acc10:acc11);
          float bb = ng ? bias1 : bias0;
          A[0]+=bb; A[1]+=bb; A[2]+=bb; A[3]+=bb;
          int ocx  = ng*16 + l15;
          int ridx = (mg*16 + qt*4) ^ ((ocx&7)<<2);
          *(f32x4*)&wcb[ocx*32 + ridx] = A;
        }
      }
    }
    BARRIER_LGKM();                        // wc visible (vmem stays in flight)

    // ---- apply: wave handles rows rg*32 + colq*8 .. +7 ----
    const int swz = (oc & 7) << 2;
    #pragma unroll
    for (int fl = 0; fl < 4; ++fl) {
      const int f   = (g*nch + ch)*4 + fl;
      const int c   = f / 9;
      const int rem = f - c*9;
      const int ki  = rem / 3;
      const int kj  = rem - ki*3;
      const float* wcb = wc + (size_t)(fl*2 + rg)*1024;
      const f32x4 wlo = *(const f32x4*)&wcb[oc*32 + ((colq*8    ) ^ swz)];
      const f32x4 whi = *(const f32x4*)&wcb[oc*32 + ((colq*8 + 4) ^ swz)];
      const __bf16* pbase = patB + (c*3 + ki)*144 + nh*4;
      #pragma unroll
      for (int rrh = 0; rrh < 4; ++rrh) {
        bf16x4 pq2 = *(const bf16x4*)(pbase + (colq*4 + rrh + kj)*8);
        float w0v = (rrh < 2) ? ((rrh == 0) ? wlo[0] : wlo[2]) : ((rrh == 2) ? whi[0] : whi[2]);
        float w1v = (rrh < 2) ? ((rrh == 0) ? wlo[1] : wlo[3]) : ((rrh == 2) ? whi[1] : whi[3]);
        #pragma unroll
        for (int q = 0; q < 4; ++q) {
          float pv = (float)pq2[q];
          oacc[rrh*2][q]   += w0v * pv;
          oacc[rrh*2+1][q] += w1v * pv;
        }
      }
    }
    BARRIER_LGKM();                        // apply done; wc reusable
  }

  // ---- epilogue: out[n, oc, X=2m+rg, Yh*32 + colq*8 .. +7] ----
  float* OP = outp + (size_t)g*OUTSZ;
  const int X = 2*m + rg;
  #pragma unroll
  for (int q = 0; q < 4; ++q) {
    int n = nh*4 + q;
    f32x4 v0, v1;
    v0[0]=oacc[0][q]; v0[1]=oacc[1][q]; v0[2]=oacc[2][q]; v0[3]=oacc[3][q];
    v1[0]=oacc[4][q]; v1[1]=oacc[5][q]; v1[2]=oacc[6][q]; v1[3]=oacc[7][q];
    float* dst = OP + (((size_t)(n*OCC + oc)*XUP + X)*YUP + Yh*32 + colq*8);
    *(f32x4*)dst     = v0;
    *(f32x4*)(dst+4) = v1;
  }
}

// ---------------------------------------------------------------------------
// Kernel 4 (G=2 only): out = P0 + P1 (deterministic)
// ---------------------------------------------------------------------------
__global__ void reduce2(const float* __restrict__ P, float* __restrict__ out) {
  int i = blockIdx.x*256 + threadIdx.x;
  if (i < OUTSZ/4) {
    f32x4 a = ((const f32x4*)P)[i];
    f32x4 b = ((const f32x4*)(P + OUTSZ))[i];
    ((f32x4*)out)[i] = a + b;
  }
}

// ---------------------------------------------------------------------------
extern "C" void kernel_launch(void* const* d_in, const int* in_sizes, int n_in,
                              void* d_out, int out_size, void* d_ws, size_t ws_size,
                              hipStream_t stream) {
  const float* F_LR = (const float*)d_in[0];
  const float* v    = (const float*)d_in[1];
  const float* w1   = (const float*)d_in[2];
  const float* b1   = (const float*)d_in[3];
  const float* w2   = (const float*)d_in[4];
  const float* b2   = (const float*)d_in[5];
  float* out = (float*)d_out;

  const size_t prepBytes = (size_t)RTOT*HID*2;          // 4,718,592 each
  const size_t need2 = 2*prepBytes + 2ull*OUTSZ*4;      // 28,311,552
  const int G   = (ws_size >= need2) ? 2 : 1;
  const int nch = 72 / G;

  __hip_bfloat16* hmidp = (__hip_bfloat16*)d_ws;
  __hip_bfloat16* w2p   = (__hip_bfloat16*)((char*)d_ws + prepBytes);
  float* P = (float*)((char*)d_ws + 2*prepBytes);
  float* target = (G == 2) ? P : out;

  const size_t shmem = 32768 + 27648 + 32768 + (size_t)nch*128*2;  // 102,400 (G=2)

  hipLaunchKernelGGL(prep_hmid, dim3(RTOT), dim3(HID), 0, stream, v, w1, b1, hmidp);
  hipLaunchKernelGGL(prep_w2,   dim3((HID*COLS)/256), dim3(256), 0, stream, w2, w2p);
  hipLaunchKernelGGL(fused_main, dim3(144*G), dim3(512), shmem, stream,
                     F_LR, hmidp, w2p, b2, target, G, nch);
  if (G == 2)
    hipLaunchKernelGGL(reduce2, dim3(OUTSZ/4/256), dim3(256), 0, stream, P, out);
}

// Round 20
// 169.612 us; speedup vs baseline: 1.2556x; 1.2556x over previous
//
#include <hip/hip_runtime.h>
#include <hip/hip_bf16.h>

// Problem constants
#define NN    8
#define CC    32
#define HH    48
#define WW    48
#define OCC   32
#define HID   256
#define FEAT  288          // C*K*K
#define RTOT  9216         // (H*S)*(W*S)
#define COLS  9216         // FEAT*OC
#define XUP   96
#define YUP   96
#define OUTSZ (NN*OCC*XUP*YUP)   // 2,359,296 floats

using bf16x8 = __attribute__((ext_vector_type(8))) __bf16;
using bf16x4 = __attribute__((ext_vector_type(4))) __bf16;
using f32x4  = __attribute__((ext_vector_type(4))) float;

// ---------------------------------------------------------------------------
// Kernel 1: hmid = relu(v @ w1 + b1), bf16, MFMA A-fragment order (verified):
//   frag = (r/16)*8 + k/32 ; lane = ((k/8)%4)*16 + r%16 ; elem = k%8
// ---------------------------------------------------------------------------
__global__ void prep_hmid(const float* __restrict__ v, const float* __restrict__ w1,
                          const float* __restrict__ b1, __hip_bfloat16* __restrict__ hmidp) {
  int r = blockIdx.x;      // 0..9215
  int t = threadIdx.x;     // 0..255 = hidden index k
  float v0 = v[r*3+0], v1 = v[r*3+1], v2 = v[r*3+2];
  float val = v0*w1[t] + v1*w1[HID+t] + v2*w1[2*HID+t] + b1[t];
  val = fmaxf(val, 0.0f);
  int dst = ((r>>4)*8 + (t>>5))*512 + ((t>>3)&3)*128 + (r&15)*8 + (t&7);
  hmidp[dst] = __float2bfloat16(val);
}

// ---------------------------------------------------------------------------
// Kernel 2: w2 -> bf16, B-fragment order grouped into 8KB slices (verified):
//   colchunk = col/128 (72), kb = k/32 (8), cg = (col%128)/16 (8),
//   lane = ((k/8)%4)*16 + col%16, elem = k%8
// ---------------------------------------------------------------------------
__global__ void prep_w2(const float* __restrict__ w2, __hip_bfloat16* __restrict__ w2p) {
  int idx = blockIdx.x*256 + threadIdx.x;   // 0 .. 256*9216-1
  int k   = idx / COLS;
  int col = idx % COLS;
  float val = w2[idx];                      // w2[k][col], row-major
  int colchunk = col >> 7;
  int cg   = (col >> 4) & 7;
  int lane = (((k>>3)&3)<<4) | (col & 15);
  int kb   = k >> 5;
  int i    = k & 7;
  int dst  = (((colchunk*8 + kb)*8 + cg)*64 + lane)*8 + i;
  w2p[dst] = __float2bfloat16(val);
}

// ---------------------------------------------------------------------------
// Kernel 3: fused GEMM + apply — R11 core (proven passing incl. post-timing),
// R20 CHANGE (one mechanism): wc PING-PONG + SINGLE barrier per chunk.
//   Old: write wc -> barrier -> apply -> barrier  (72 rendezvous total).
//   New: write wcb[ch&1] -> barrier -> apply from wcb[ch&1]; next chunk
//   writes the OTHER buffer, so no trailing barrier is needed. Wave X's next
//   write to wcb[ch&1] is at ch+2, after barrier(ch+1), which wave Y signals
//   only after its apply(ch) ds_reads retired (barrier's own lgkmcnt(0)).
//   36 rendezvous total -> tests the "barrier rendezvous is the hidden
//   per-chunk cost" hypothesis on the best-known kernel.
// LDS (dynamic): pat 27648 + wc 2x16384 + biasL 9216 = 69,632 -> 2 blocks/CU.
// ---------------------------------------------------------------------------
#define BARRIER_LGKM() do {                              \
    asm volatile("s_waitcnt lgkmcnt(0)" ::: "memory");   \
    __builtin_amdgcn_sched_barrier(0);                   \
    __builtin_amdgcn_s_barrier();                        \
  } while (0)

#define ISSUE_HALF(SET, CH, H) do {                                              \
    const char* _b = w2base + ((size_t)((CH)*8 + (H)*4))*8192 + wv*2048          \
                     + (size_t)lane*16;                                          \
    _Pragma("unroll")                                                            \
    for (int _i = 0; _i < 4; ++_i) {                                             \
      SET[0][_i] = *(const bf16x8*)(_b + _i*8192);                               \
      SET[1][_i] = *(const bf16x8*)(_b + _i*8192 + 1024);                        \
    }                                                                            \
  } while (0)

__launch_bounds__(256, 2)
__global__ void fused_main(const float* __restrict__ F_LR,
                           const __hip_bfloat16* __restrict__ hmidp,
                           const __hip_bfloat16* __restrict__ w2p,
                           const float* __restrict__ b2,
                           float* __restrict__ outp,
                           int G, int nch) {
  extern __shared__ __align__(16) char smem[];
  __bf16* patB  = (__bf16*)smem;                 // 27648B: pat[c][ki][wi(18)][n(8)]
  float*  wcbuf = (float*)(smem + 27648);        // 2 x 16384B ping-pong
  __bf16* biasL = (__bf16*)(smem + 60416);       // nch*128 bf16

  const int tid  = threadIdx.x;
  const int lane = tid & 63;
  const int wv   = tid >> 6;
  const int blk  = blockIdx.x;
  int rowtile, g;
  if (G == 2) {            // XCD-chunked decode (grid = 576, 72 blocks per XCD)
    int xcd = blk & 7;
    int j   = blk >> 3;    // 0..71
    g       = xcd & 1;
    rowtile = (xcd >> 1)*72 + j;
  } else {
    rowtile = blk;
    g       = 0;
  }
  const int X  = rowtile / 3;
  const int Yh = rowtile - X*3;
  const int h  = X >> 1;
  const int w0 = Yh * 16;
  const int l15 = lane & 15;
  const int qt  = lane >> 4;
  const int oc  = lane & 31;
  const int nh  = lane >> 5;

  const char* w2base = (const char*)w2p + (size_t)g*nch*65536;

  // ---- A fragments -> registers (16 coalesced b128 loads) ----
  bf16x8 a[2][8];
  {
    const bf16x8* ap = reinterpret_cast<const bf16x8*>(hmidp) + (size_t)rowtile*1024 + lane;
    #pragma unroll
    for (int mg = 0; mg < 2; ++mg)
      #pragma unroll
      for (int kb = 0; kb < 8; ++kb) a[mg][kb] = ap[(mg*8 + kb)*64];
  }

  // ---- bias table -> LDS (bf16, one-time) ----
  for (int i = tid; i < nch*128; i += 256)
    biasL[i] = (__bf16)b2[g*nch*128 + i];

  // ---- stage patches: pat[c][ki][wi][n]; thread = (n,c) ----
  {
    const int n = tid >> 5, c = tid & 31;
    const float* fsrc = F_LR + ((size_t)(n*CC + c)*HH)*WW;
    #pragma unroll
    for (int ki = 0; ki < 3; ++ki) {
      int hh = h - 1 + ki;
      bool hok = (unsigned)hh < (unsigned)HH;
      #pragma unroll
      for (int wi = 0; wi < 18; ++wi) {
        int ww = w0 - 1 + wi;
        float val = (hok && (unsigned)ww < (unsigned)WW) ? fsrc[hh*WW + ww] : 0.f;
        patB[((c*3 + ki)*18 + wi)*8 + n] = (__bf16)val;
      }
    }
  }
  BARRIER_LGKM();

  float oacc[8][4];
  #pragma unroll
  for (int i = 0; i < 8; ++i)
    { oacc[i][0]=0.f; oacc[i][1]=0.f; oacc[i][2]=0.f; oacc[i][3]=0.f; }

  // ---- B double buffer: two half-chunk register sets ----
  bf16x8 bA[2][4], bB[2][4];
  ISSUE_HALF(bA, 0, 0);
  ISSUE_HALF(bB, 0, 1);

  for (int ch = 0; ch < nch; ++ch) {
    f32x4 acc00 = {0,0,0,0}, acc01 = {0,0,0,0}, acc10 = {0,0,0,0}, acc11 = {0,0,0,0};

    // ---- consume half A (slices 0..3), then refill for ch+1 ----
    #pragma unroll
    for (int s = 0; s < 4; ++s) {
      acc00 = __builtin_amdgcn_mfma_f32_16x16x32_bf16(a[0][s], bA[0][s], acc00, 0,0,0);
      acc01 = __builtin_amdgcn_mfma_f32_16x16x32_bf16(a[0][s], bA[1][s], acc01, 0,0,0);
      acc10 = __builtin_amdgcn_mfma_f32_16x16x32_bf16(a[1][s], bA[0][s], acc10, 0,0,0);
      acc11 = __builtin_amdgcn_mfma_f32_16x16x32_bf16(a[1][s], bA[1][s], acc11, 0,0,0);
    }
    if (ch + 1 < nch) { ISSUE_HALF(bA, ch+1, 0); }

    // ---- consume half B (slices 4..7), then refill for ch+1 ----
    #pragma unroll
    for (int s = 0; s < 4; ++s) {
      acc00 = __builtin_amdgcn_mfma_f32_16x16x32_bf16(a[0][4+s], bB[0][s], acc00, 0,0,0);
      acc01 = __builtin_amdgcn_mfma_f32_16x16x32_bf16(a[0][4+s], bB[1][s], acc01, 0,0,0);
      acc10 = __builtin_amdgcn_mfma_f32_16x16x32_bf16(a[1][4+s], bB[0][s], acc10, 0,0,0);
      acc11 = __builtin_amdgcn_mfma_f32_16x16x32_bf16(a[1][4+s], bB[1][s], acc11, 0,0,0);
    }
    if (ch + 1 < nch) { ISSUE_HALF(bB, ch+1, 1); }

    // ---- wc write (ping-pong buffer ch&1): wc[fl(=wv)][oc][r^swz] ----
    float* wcb = wcbuf + (size_t)(ch & 1)*4096;
    {
      float bias0 = (float)biasL[ch*128 + wv*32 + l15];
      float bias1 = (float)biasL[ch*128 + wv*32 + 16 + l15];
      #pragma unroll
      for (int mg = 0; mg < 2; ++mg) {
        #pragma unroll
        for (int ng = 0; ng < 2; ++ng) {
          f32x4 A = (mg==0) ? (ng==0?acc00:acc01) : (ng==0?acc10:acc11);
          float bb = ng ? bias1 : bias0;
          A[0]+=bb; A[1]+=bb; A[2]+=bb; A[3]+=bb;
          int ocx  = ng*16 + l15;
          int ridx = (mg*16 + qt*4) ^ ((ocx&7)<<2);
          *(f32x4*)&wcb[wv*1024 + ocx*32 + ridx] = A;
        }
      }
    }
    BARRIER_LGKM();                        // the ONLY barrier per chunk

    // ---- apply (reads wcb[ch&1]; next chunk writes the other buffer) ----
    const int swz = (oc & 7) << 2;
    #pragma unroll
    for (int fl = 0; fl < 4; ++fl) {
      const int f   = (g*nch + ch)*4 + fl;
      const int c   = f / 9;
      const int rem = f - c*9;
      const int ki  = rem / 3;
      const int kj  = rem - ki*3;
      const f32x4 wlo = *(const f32x4*)&wcb[fl*1024 + oc*32 + ((wv*8    ) ^ swz)];
      const f32x4 whi = *(const f32x4*)&wcb[fl*1024 + oc*32 + ((wv*8 + 4) ^ swz)];
      const __bf16* pbase = patB + (c*3 + ki)*144 + nh*4;
      #pragma unroll
      for (int rrh = 0; rrh < 4; ++rrh) {
        bf16x4 pq = *(const bf16x4*)(pbase + (wv*4 + rrh + kj)*8);
        float w0v = (rrh < 2) ? ((rrh == 0) ? wlo[0] : wlo[2]) : ((rrh == 2) ? whi[0] : whi[2]);
        float w1v = (rrh < 2) ? ((rrh == 0) ? wlo[1] : wlo[3]) : ((rrh == 2) ? whi[1] : whi[3]);
        #pragma unroll
        for (int q = 0; q < 4; ++q) {
          float pv = (float)pq[q];
          oacc[rrh*2][q]   += w0v * pv;
          oacc[rrh*2+1][q] += w1v * pv;
        }
      }
    }
    // no trailing barrier: next chunk writes the other wc buffer
  }

  // ---- epilogue: out[n, oc, X, Yh*32 + wv*8 .. +7] ----
  float* OP = outp + (size_t)g*OUTSZ;
  #pragma unroll
  for (int q = 0; q < 4; ++q) {
    int n = nh*4 + q;
    f32x4 v0, v1;
    v0[0]=oacc[0][q]; v0[1]=oacc[1][q]; v0[2]=oacc[2][q]; v0[3]=oacc[3][q];
    v1[0]=oacc[4][q]; v1[1]=oacc[5][q]; v1[2]=oacc[6][q]; v1[3]=oacc[7][q];
    float* dst = OP + (((size_t)(n*OCC + oc)*XUP + X)*YUP + Yh*32 + wv*8);
    *(f32x4*)dst     = v0;
    *(f32x4*)(dst+4) = v1;
  }
}

// ---------------------------------------------------------------------------
// Kernel 4 (G=2 only): out = P0 + P1 (deterministic)
// ---------------------------------------------------------------------------
__global__ void reduce2(const float* __restrict__ P, float* __restrict__ out) {
  int i = blockIdx.x*256 + threadIdx.x;
  if (i < OUTSZ/4) {
    f32x4 a = ((const f32x4*)P)[i];
    f32x4 b = ((const f32x4*)(P + OUTSZ))[i];
    ((f32x4*)out)[i] = a + b;
  }
}

// ---------------------------------------------------------------------------
extern "C" void kernel_launch(void* const* d_in, const int* in_sizes, int n_in,
                              void* d_out, int out_size, void* d_ws, size_t ws_size,
                              hipStream_t stream) {
  const float* F_LR = (const float*)d_in[0];
  const float* v    = (const float*)d_in[1];
  const float* w1   = (const float*)d_in[2];
  const float* b1   = (const float*)d_in[3];
  const float* w2   = (const float*)d_in[4];
  const float* b2   = (const float*)d_in[5];
  float* out = (float*)d_out;

  const size_t prepBytes = (size_t)RTOT*HID*2;          // 4,718,592 each
  const size_t need2 = 2*prepBytes + 2ull*OUTSZ*4;      // 28,311,552
  const int G   = (ws_size >= need2) ? 2 : 1;
  const int nch = 72 / G;

  __hip_bfloat16* hmidp = (__hip_bfloat16*)d_ws;
  __hip_bfloat16* w2p   = (__hip_bfloat16*)((char*)d_ws + prepBytes);
  float* P = (float*)((char*)d_ws + 2*prepBytes);
  float* target = (G == 2) ? P : out;

  const size_t shmem = 27648 + 2*16384 + (size_t)nch*128*2;   // 69,632 (G=2)

  hipLaunchKernelGGL(prep_hmid, dim3(RTOT), dim3(HID), 0, stream, v, w1, b1, hmidp);
  hipLaunchKernelGGL(prep_w2,   dim3((HID*COLS)/256), dim3(256), 0, stream, w2, w2p);
  hipLaunchKernelGGL(fused_main, dim3(288*G), dim3(256), shmem, stream,
                     F_LR, hmidp, w2p, b2, target, G, nch);
  if (G == 2)
    hipLaunchKernelGGL(reduce2, dim3(OUTSZ/4/256), dim3(256), 0, stream, P, out);
}